// Round 5
// baseline (201.771 us; speedup 1.0000x reference)
//
#include <hip/hip_runtime.h>

typedef __attribute__((ext_vector_type(8))) short short8;
typedef __attribute__((ext_vector_type(4))) float f32x4;

// ---- d_out scratch (float offsets), consumed before k2 overwrites:
//   xa     bf16[16777216] -> [0, 8388608) floats
//   waT    bf16[ 4194304] -> [8388608, 10485760) floats   (W1^T, [1024][4096])
//   plogit f32[4096*64]   -> [10485760, 10747904) floats  (split-K x n-tile partials)
// ---- d_ws layout (bytes):
//   k_arr  int[4096]     [0, 16384)
//   sp_arr f32[4096]     [16384, 32768)
//   l1rows f64[4096]     [32768, 65536)

__device__ __forceinline__ unsigned short bf16rn(float f) {
    unsigned u = __float_as_uint(f);
    return (unsigned short)((u + 0x7fffu + ((u >> 16) & 1u)) >> 16);
}

__device__ __forceinline__ void gl16(const void* g, void* l) {
    __builtin_amdgcn_global_load_lds(
        (const __attribute__((address_space(1))) void*)g,
        (__attribute__((address_space(3))) void*)l, 16, 0, 0);
}

// ---------------- k0a: x (fp32) -> xa (bf16)
__global__ __launch_bounds__(256) void k0a_cvtx(const float* __restrict__ x,
                                                unsigned short* __restrict__ xa)
{
    int i = blockIdx.x * 256 + threadIdx.x;
    float4 v = ((const float4*)x)[i];
    ushort4 a;
    a.x = bf16rn(v.x); a.y = bf16rn(v.y); a.z = bf16rn(v.z); a.w = bf16rn(v.w);
    ((ushort4*)xa)[i] = a;
}

// ---------------- k0b: W1 [4096][1024] fp32 -> waT [1024][4096] bf16 (transpose)
__global__ __launch_bounds__(256) void k0b_cvtw(const float* __restrict__ W1,
                                                unsigned short* __restrict__ waT)
{
    __shared__ float ts[64][65];
    const int n0 = blockIdx.x * 64;
    const int k0 = blockIdx.y * 64;
    const int tid = threadIdx.x;
    #pragma unroll
    for (int it = 0; it < 16; it++) {
        int idx = tid + it * 256;
        int r = idx >> 6, c = idx & 63;
        ts[r][c] = W1[(size_t)(k0 + r) * 1024 + (n0 + c)];
    }
    __syncthreads();
    #pragma unroll
    for (int it = 0; it < 16; it++) {
        int idx = tid + it * 256;
        int n = idx >> 6, kk = idx & 63;
        waT[(size_t)(n0 + n) * 4096 + (k0 + kk)] = bf16rn(ts[kk][n]);
    }
}

// ---------------- k1est: bf16 MFMA partial logits — split-K(4), BK=32 double-buffered
// tile M=128 x N=64 x KC=1024; 4 waves; LDS 24KB -> 6 blocks/CU resident.
// grid 2048 = 4 kc x 32 bm x 16 bn; XCD-chunked swizzle keeps (bm,bn) neighbors
// within one k-chunk on the same XCD for L2 panel sharing.
__global__ __launch_bounds__(256) void k1est(const unsigned short* __restrict__ xa,
                                             const unsigned short* __restrict__ waT,
                                             const float* __restrict__ b1,
                                             const float* __restrict__ W2,
                                             float* __restrict__ plogit)
{
    __shared__ alignas(16) unsigned short Ab[2][4][128][8];   // 2 x 8KB
    __shared__ alignas(16) unsigned short Bb[2][4][64][8];    // 2 x 4KB

    const int bid = blockIdx.x;
    const int wgid = (bid & 7) * 256 + (bid >> 3);   // 2048 % 8 == 0, bijective
    const int kc = wgid >> 9;                        // 0..3
    const int rem = wgid & 511;
    const int bm = rem >> 4, bn = rem & 15;
    const int n0 = bn * 64, m0 = bm * 128;
    const int kbase = kc * 1024;
    const int tid = threadIdx.x;
    const int l = tid & 63, w = tid >> 6;
    const int arow = l & 15, kg = l >> 4;

    // staging slots (wave-linear 16B slots -> gload_lds-compatible, conflict-free)
    // A: 512 slots/step (128 rows x 32k): slot=(w*2+i)*64+l; g=slot>>7; row=slot&127
    int aslot[2], arowg[2], ag[2];
    #pragma unroll
    for (int i = 0; i < 2; i++) {
        aslot[i] = (w * 2 + i) * 64 + l;
        ag[i] = aslot[i] >> 7;
        arowg[i] = aslot[i] & 127;
    }
    // B: 256 slots/step (64 n x 32k): slot=w*64+l; g=slot>>6; n=slot&63
    const int bslot = w * 64 + l;
    const int bg = bslot >> 6, bnn = bslot & 63;

    f32x4 acc[2][4];
    #pragma unroll
    for (int i = 0; i < 2; i++)
        #pragma unroll
        for (int j = 0; j < 4; j++) acc[i][j] = (f32x4)0.0f;

    // prologue: stage step 0 into buffer 0
    #pragma unroll
    for (int i = 0; i < 2; i++)
        gl16(xa + (size_t)(m0 + arowg[i]) * 4096 + kbase + ag[i] * 8,
             &Ab[0][0][aslot[i]][0]);
    gl16(waT + (size_t)(n0 + bnn) * 4096 + kbase + bg * 8,
         &Bb[0][0][bslot][0]);
    __syncthreads();

    for (int t = 0; t < 32; t++) {
        const int cur = t & 1;
        if (t < 31) {
            const int k0 = kbase + (t + 1) * 32;
            #pragma unroll
            for (int i = 0; i < 2; i++)
                gl16(xa + (size_t)(m0 + arowg[i]) * 4096 + k0 + ag[i] * 8,
                     &Ab[cur ^ 1][0][aslot[i]][0]);
            gl16(waT + (size_t)(n0 + bnn) * 4096 + k0 + bg * 8,
                 &Bb[cur ^ 1][0][bslot][0]);
        }
        short8 af[2], bf[4];
        #pragma unroll
        for (int mf = 0; mf < 2; mf++)
            af[mf] = *(const short8*)&Ab[cur][kg][w * 32 + mf * 16 + arow][0];
        #pragma unroll
        for (int nf = 0; nf < 4; nf++)
            bf[nf] = *(const short8*)&Bb[cur][kg][nf * 16 + arow][0];
        #pragma unroll
        for (int mf = 0; mf < 2; mf++)
            #pragma unroll
            for (int nf = 0; nf < 4; nf++)
                acc[mf][nf] = __builtin_amdgcn_mfma_f32_16x16x32_bf16(
                    af[mf], bf[nf], acc[mf][nf], 0, 0, 0);
        __syncthreads();
    }

    // epilogue: h = acc + b1, relu, dot W2 over this block's 64 cols (K-chunk partial)
    // C/D layout (m89): col = lane&15 (N idx), row = (lane>>4)*4 + i (M idx)
    #pragma unroll
    for (int mf = 0; mf < 2; mf++) {
        #pragma unroll
        for (int i = 0; i < 4; i++) {
            float p = 0.0f;
            #pragma unroll
            for (int nf = 0; nf < 4; nf++) {
                int n = n0 + nf * 16 + arow;
                float h = acc[mf][nf][i] + b1[n];
                if (h > 0.0f) p += h * W2[n];
            }
            #pragma unroll
            for (int o = 1; o < 16; o <<= 1) p += __shfl_xor(p, o, 64);
            if (arow == 0)
                plogit[(size_t)(m0 + w * 32 + mf * 16 + kg * 4 + i) * 64 + kc * 16 + bn] = p;
        }
    }
}

// ---------------- k1b: per-row logit -> sigmoid -> sparsity/k (sums 64 partials)
__global__ __launch_bounds__(256) void k1b_k(const float* __restrict__ plogit,
                                             const float* __restrict__ b2,
                                             int* __restrict__ k_arr,
                                             float* __restrict__ sp_arr)
{
    int row = blockIdx.x * 256 + threadIdx.x;
    float lg = 0.0f;
    #pragma unroll
    for (int t = 0; t < 64; t++) lg += plogit[(size_t)row * 64 + t];
    double s  = 1.0 / (1.0 + exp(-(double)(lg + b2[0])));
    double sp = 0.05 + 0.25 * s;
    int k = (int)rint(4096.0 * (1.0 - sp));
    if (k < 1) k = 1;
    if (k > 4096) k = 4096;
    k_arr[row] = k;
    sp_arr[row] = (float)sp;
}

// ---------------- k2: per-row radix-select threshold + all big outputs
__global__ __launch_bounds__(256) void k2_row(const float* __restrict__ x,
                                              const int* __restrict__ k_arr,
                                              const float* __restrict__ sp_arr,
                                              float* __restrict__ out_sparse,
                                              float* __restrict__ out_mask,
                                              float* __restrict__ out_spars,
                                              float* __restrict__ out_actual,
                                              double* __restrict__ l1rows)
{
    __shared__ unsigned bits[4096];
    __shared__ unsigned hist[256];
    __shared__ unsigned wsum[4];
    __shared__ int cnt_w[4];
    __shared__ double l1_w[4];
    __shared__ int sel_s;
    __shared__ unsigned selexc_s;

    const int row = blockIdx.x;
    const int tid = threadIdx.x;
    const int lane = tid & 63, wid = tid >> 6;
    const float* xr = x + (size_t)row * 4096;

    for (int i = tid; i < 1024; i += 256) {
        uint4 v = ((const uint4*)xr)[i];
        bits[i * 4 + 0] = v.x;
        bits[i * 4 + 1] = v.y;
        bits[i * 4 + 2] = v.z;
        bits[i * 4 + 3] = v.w;
    }
    if (tid == 0) out_spars[row] = sp_arr[row];
    __syncthreads();

    int krem = k_arr[row];
    unsigned prefix = 0;
    for (int pass = 0; pass < 4; pass++) {
        int shift = 24 - pass * 8;
        hist[tid] = 0;
        __syncthreads();
        for (int i = tid; i < 4096; i += 256) {
            unsigned a = bits[i] & 0x7fffffffu;
            bool ok = (pass == 0) || ((a >> (shift + 8)) == prefix);
            if (ok) atomicAdd(&hist[(a >> shift) & 255u], 1u);
        }
        __syncthreads();
        unsigned v = hist[tid];
        unsigned sc = v;
        #pragma unroll
        for (int o = 1; o < 64; o <<= 1) {
            unsigned n = __shfl_up(sc, o, 64);
            if (lane >= o) sc += n;
        }
        if (lane == 63) wsum[wid] = sc;
        __syncthreads();
        unsigned off = 0;
        for (int ww = 0; ww < wid; ww++) off += wsum[ww];
        sc += off;
        unsigned exc = sc - v;
        if ((int)sc >= krem && (int)exc < krem) { sel_s = tid; selexc_s = exc; }
        __syncthreads();
        prefix = (prefix << 8) | (unsigned)sel_s;
        krem -= (int)selexc_s;
        __syncthreads();
    }
    const unsigned thr = prefix;   // bit pattern of kth smallest |x|

    int cnt = 0;
    double l1 = 0.0;
    float* os = out_sparse + (size_t)row * 4096;
    float* om = out_mask + (size_t)row * 4096;
    for (int i = tid; i < 1024; i += 256) {
        float4 sv, mv;
        #pragma unroll
        for (int j = 0; j < 4; j++) {
            unsigned b = bits[i * 4 + j];
            unsigned a = b & 0x7fffffffu;
            bool m = a > thr;
            (&sv.x)[j] = m ? __uint_as_float(b) : 0.0f;
            (&mv.x)[j] = m ? 1.0f : 0.0f;
            if (m) { cnt++; l1 += (double)__uint_as_float(a); }
        }
        ((float4*)os)[i] = sv;
        ((float4*)om)[i] = mv;
    }
    #pragma unroll
    for (int o = 32; o > 0; o >>= 1) {
        cnt += __shfl_down(cnt, o, 64);
        l1  += __shfl_down(l1,  o, 64);
    }
    if (lane == 0) { cnt_w[wid] = cnt; l1_w[wid] = l1; }
    __syncthreads();
    if (tid == 0) {
        int c    = cnt_w[0] + cnt_w[1] + cnt_w[2] + cnt_w[3];
        double l = l1_w[0] + l1_w[1] + l1_w[2] + l1_w[3];
        out_actual[row] = (float)c / 4096.0f;
        l1rows[row] = l;
    }
}

// ---------------- k3: deterministic l1 mean (f64)
__global__ __launch_bounds__(256) void k3_l1(const double* __restrict__ l1rows,
                                             float* __restrict__ out_l1)
{
    __shared__ double sm[256];
    int tid = threadIdx.x;
    double s = 0.0;
    for (int i = tid; i < 4096; i += 256) s += l1rows[i];
    sm[tid] = s;
    __syncthreads();
    for (int st = 128; st > 0; st >>= 1) {
        if (tid < st) sm[tid] += sm[tid + st];
        __syncthreads();
    }
    if (tid == 0) out_l1[0] = (float)(sm[0] / 4096.0);
}

extern "C" void kernel_launch(void* const* d_in, const int* in_sizes, int n_in,
                              void* d_out, int out_size, void* d_ws, size_t ws_size,
                              hipStream_t stream)
{
    const float* x  = (const float*)d_in[0];
    const float* W1 = (const float*)d_in[1];
    const float* b1 = (const float*)d_in[2];
    const float* W2 = (const float*)d_in[3];
    const float* b2 = (const float*)d_in[4];

    float* out        = (float*)d_out;
    float* out_sparse = out;                       // [4096,4096]
    float* out_mask   = out + 16777216;            // [4096,4096]
    float* out_spars  = out + 33554432;            // [4096,1]
    float* out_actual = out + 33558528;            // [4096]
    float* out_l1     = out + 33562624;            // [1]

    // big scratch inside d_out's sparse region (consumed before k2 writes it)
    unsigned short* xa  = (unsigned short*)(out);               // 32MB
    unsigned short* waT = (unsigned short*)(out + 8388608);     // 8MB
    float*          plogit = out + 10485760;                    // 1MB, [4096][64]

    // small hot arrays in d_ws (read by k2/k3 -> must not alias outputs)
    char* ws = (char*)d_ws;
    int*    k_arr  = (int*)(ws);               // 16KB
    float*  sp_arr = (float*)(ws + 16384);     // 16KB
    double* l1rows = (double*)(ws + 32768);    // 32KB

    k0a_cvtx<<<16384, 256, 0, stream>>>(x, xa);
    k0b_cvtw<<<dim3(16, 64), 256, 0, stream>>>(W1, waT);
    k1est<<<2048, 256, 0, stream>>>(xa, waT, b1, W2, plogit);
    k1b_k<<<16, 256, 0, stream>>>(plogit, b2, k_arr, sp_arr);
    k2_row<<<4096, 256, 0, stream>>>(x, k_arr, sp_arr, out_sparse, out_mask,
                                     out_spars, out_actual, l1rows);
    k3_l1<<<1, 256, 0, stream>>>(l1rows, out_l1);
}

// Round 6
// 182.402 us; speedup vs baseline: 1.1062x; 1.1062x over previous
//
#include <hip/hip_runtime.h>

typedef __attribute__((ext_vector_type(8))) short short8;
typedef __attribute__((ext_vector_type(4))) float f32x4;

// ---- d_out scratch (float offsets), consumed before k2 overwrites:
//   xa     bf16[16777216] -> [0, 8388608) floats
//   waT    bf16[ 4194304] -> [8388608, 10485760) floats   (W1^T, [1024][4096])
//   plogit f32[4096*32]   -> [10485760, 10616832) floats  (kc x bn partials)
// ---- d_ws layout (bytes):
//   k_arr  int[4096]     [0, 16384)
//   sp_arr f32[4096]     [16384, 32768)
//   l1rows f64[4096]     [32768, 65536)

__device__ __forceinline__ unsigned short bf16rn(float f) {
    unsigned u = __float_as_uint(f);
    return (unsigned short)((u + 0x7fffu + ((u >> 16) & 1u)) >> 16);
}

__device__ __forceinline__ void gl16(const void* g, void* l) {
    __builtin_amdgcn_global_load_lds(
        (const __attribute__((address_space(1))) void*)g,
        (__attribute__((address_space(3))) void*)l, 16, 0, 0);
}

// ---------------- k0a: x (fp32) -> xa (bf16)
__global__ __launch_bounds__(256) void k0a_cvtx(const float* __restrict__ x,
                                                unsigned short* __restrict__ xa)
{
    int i = blockIdx.x * 256 + threadIdx.x;
    float4 v = ((const float4*)x)[i];
    ushort4 a;
    a.x = bf16rn(v.x); a.y = bf16rn(v.y); a.z = bf16rn(v.z); a.w = bf16rn(v.w);
    ((ushort4*)xa)[i] = a;
}

// ---------------- k0b: W1 [4096][1024] fp32 -> waT [1024][4096] bf16 (transpose)
__global__ __launch_bounds__(256) void k0b_cvtw(const float* __restrict__ W1,
                                                unsigned short* __restrict__ waT)
{
    __shared__ float ts[64][65];
    const int n0 = blockIdx.x * 64;
    const int k0 = blockIdx.y * 64;
    const int tid = threadIdx.x;
    #pragma unroll
    for (int it = 0; it < 16; it++) {
        int idx = tid + it * 256;
        int r = idx >> 6, c = idx & 63;
        ts[r][c] = W1[(size_t)(k0 + r) * 1024 + (n0 + c)];
    }
    __syncthreads();
    #pragma unroll
    for (int it = 0; it < 16; it++) {
        int idx = tid + it * 256;
        int n = idx >> 6, kk = idx & 63;
        waT[(size_t)(n0 + n) * 4096 + (k0 + kk)] = bf16rn(ts[kk][n]);
    }
}

// ---------------- k1est: bf16 MFMA partial logits — BM=256 x BN=128, split-K(4)
// 512 threads = 8 waves (4m x 2n), wave tile 64x64 (4x4 frags), BK=32 double-buffered.
// Traffic: A 256MB + B 128MB (half of the 64x128 tiling) — attacks the ~7.5 TB/s
// LLC-path ceiling observed in rounds 3-5.
__global__ __launch_bounds__(512, 4) void k1est(const unsigned short* __restrict__ xa,
                                                const unsigned short* __restrict__ waT,
                                                const float* __restrict__ b1,
                                                const float* __restrict__ W2,
                                                float* __restrict__ plogit)
{
    __shared__ alignas(16) unsigned short Ab[2][4][256][8];   // 2 x 16KB
    __shared__ alignas(16) unsigned short Bb[2][4][128][8];   // 2 x 8KB

    const int bid = blockIdx.x;
    const int wgid = (bid & 7) * 64 + (bid >> 3);   // 512 % 8 == 0, bijective XCD chunks
    const int kc = wgid >> 7;                       // 0..3
    const int rem = wgid & 127;
    const int bm = rem >> 3, bn = rem & 7;          // 16 x 8
    const int m0 = bm * 256, n0 = bn * 128;
    const int kbase = kc * 1024;
    const int tid = threadIdx.x;
    const int l = tid & 63, w = tid >> 6;
    const int wm = w >> 1, wn = w & 1;
    const int arow = l & 15, kg = l >> 4;

    // staging slots (wave-linear 16B slots; linear LDS dest for gload_lds)
    // A: 1024 slots/step (256 rows x 32k): slot=(w*2+j)*64+l; g=slot>>8; row=slot&255
    int aslot[2], arowg[2], ag[2];
    #pragma unroll
    for (int j = 0; j < 2; j++) {
        aslot[j] = (w * 2 + j) * 64 + l;
        ag[j] = aslot[j] >> 8;
        arowg[j] = aslot[j] & 255;
    }
    // B: 512 slots/step (128 n x 32k): slot=w*64+l; g=slot>>7; n=slot&127
    const int bslot = w * 64 + l;
    const int bg = bslot >> 7, bnn = bslot & 127;

    f32x4 acc[4][4];
    #pragma unroll
    for (int i = 0; i < 4; i++)
        #pragma unroll
        for (int j = 0; j < 4; j++) acc[i][j] = (f32x4)0.0f;

    // prologue: stage step 0 into buffer 0
    #pragma unroll
    for (int j = 0; j < 2; j++)
        gl16(xa + (size_t)(m0 + arowg[j]) * 4096 + kbase + ag[j] * 8,
             ((unsigned short*)&Ab[0][0][0][0]) + aslot[j] * 8);
    gl16(waT + (size_t)(n0 + bnn) * 4096 + kbase + bg * 8,
         ((unsigned short*)&Bb[0][0][0][0]) + bslot * 8);
    __syncthreads();

    for (int t = 0; t < 32; t++) {
        const int cur = t & 1;
        if (t < 31) {
            const int k0 = kbase + (t + 1) * 32;
            #pragma unroll
            for (int j = 0; j < 2; j++)
                gl16(xa + (size_t)(m0 + arowg[j]) * 4096 + k0 + ag[j] * 8,
                     ((unsigned short*)&Ab[cur ^ 1][0][0][0]) + aslot[j] * 8);
            gl16(waT + (size_t)(n0 + bnn) * 4096 + k0 + bg * 8,
                 ((unsigned short*)&Bb[cur ^ 1][0][0][0]) + bslot * 8);
        }
        short8 af[4], bf[4];
        #pragma unroll
        for (int mf = 0; mf < 4; mf++)
            af[mf] = *(const short8*)&Ab[cur][kg][wm * 64 + mf * 16 + arow][0];
        #pragma unroll
        for (int nf = 0; nf < 4; nf++)
            bf[nf] = *(const short8*)&Bb[cur][kg][wn * 64 + nf * 16 + arow][0];
        #pragma unroll
        for (int mf = 0; mf < 4; mf++)
            #pragma unroll
            for (int nf = 0; nf < 4; nf++)
                acc[mf][nf] = __builtin_amdgcn_mfma_f32_16x16x32_bf16(
                    af[mf], bf[nf], acc[mf][nf], 0, 0, 0);
        __syncthreads();
    }

    // epilogue: h = acc + b1, relu, dot W2 over this wave's 64 cols (K-chunk partial)
    // C/D layout (m89): col = lane&15 (N idx), row = (lane>>4)*4 + i (M idx)
    #pragma unroll
    for (int mf = 0; mf < 4; mf++) {
        #pragma unroll
        for (int i = 0; i < 4; i++) {
            float p = 0.0f;
            #pragma unroll
            for (int nf = 0; nf < 4; nf++) {
                int n = n0 + wn * 64 + nf * 16 + arow;
                float h = acc[mf][nf][i] + b1[n];
                if (h > 0.0f) p += h * W2[n];
            }
            #pragma unroll
            for (int o = 1; o < 16; o <<= 1) p += __shfl_xor(p, o, 64);
            if (arow == 0) {
                int row = m0 + wm * 64 + mf * 16 + kg * 4 + i;
                // two waves (wn=0,1) share a row-range -> distinct partial columns
                atomicAdd(&plogit[(size_t)row * 32 + kc * 8 + bn], p);
            }
        }
    }
}

// ---------------- k1z: zero plogit (atomicAdd accumulation target)
__global__ __launch_bounds__(256) void k1z_zero(float* __restrict__ plogit)
{
    plogit[blockIdx.x * 256 + threadIdx.x] = 0.0f;
}

// ---------------- k1b: per-row logit -> sigmoid -> sparsity/k (sums 32 partials)
__global__ __launch_bounds__(256) void k1b_k(const float* __restrict__ plogit,
                                             const float* __restrict__ b2,
                                             int* __restrict__ k_arr,
                                             float* __restrict__ sp_arr)
{
    int row = blockIdx.x * 256 + threadIdx.x;
    float lg = 0.0f;
    #pragma unroll
    for (int t = 0; t < 32; t++) lg += plogit[(size_t)row * 32 + t];
    double s  = 1.0 / (1.0 + exp(-(double)(lg + b2[0])));
    double sp = 0.05 + 0.25 * s;
    int k = (int)rint(4096.0 * (1.0 - sp));
    if (k < 1) k = 1;
    if (k > 4096) k = 4096;
    k_arr[row] = k;
    sp_arr[row] = (float)sp;
}

// ---------------- k2: per-row radix-select threshold + all big outputs
__global__ __launch_bounds__(256) void k2_row(const float* __restrict__ x,
                                              const int* __restrict__ k_arr,
                                              const float* __restrict__ sp_arr,
                                              float* __restrict__ out_sparse,
                                              float* __restrict__ out_mask,
                                              float* __restrict__ out_spars,
                                              float* __restrict__ out_actual,
                                              double* __restrict__ l1rows)
{
    __shared__ unsigned bits[4096];
    __shared__ unsigned hist[256];
    __shared__ unsigned wsum[4];
    __shared__ int cnt_w[4];
    __shared__ double l1_w[4];
    __shared__ int sel_s;
    __shared__ unsigned selexc_s;

    const int row = blockIdx.x;
    const int tid = threadIdx.x;
    const int lane = tid & 63, wid = tid >> 6;
    const float* xr = x + (size_t)row * 4096;

    for (int i = tid; i < 1024; i += 256) {
        uint4 v = ((const uint4*)xr)[i];
        bits[i * 4 + 0] = v.x;
        bits[i * 4 + 1] = v.y;
        bits[i * 4 + 2] = v.z;
        bits[i * 4 + 3] = v.w;
    }
    if (tid == 0) out_spars[row] = sp_arr[row];
    __syncthreads();

    int krem = k_arr[row];
    unsigned prefix = 0;
    for (int pass = 0; pass < 4; pass++) {
        int shift = 24 - pass * 8;
        hist[tid] = 0;
        __syncthreads();
        for (int i = tid; i < 4096; i += 256) {
            unsigned a = bits[i] & 0x7fffffffu;
            bool ok = (pass == 0) || ((a >> (shift + 8)) == prefix);
            if (ok) atomicAdd(&hist[(a >> shift) & 255u], 1u);
        }
        __syncthreads();
        unsigned v = hist[tid];
        unsigned sc = v;
        #pragma unroll
        for (int o = 1; o < 64; o <<= 1) {
            unsigned n = __shfl_up(sc, o, 64);
            if (lane >= o) sc += n;
        }
        if (lane == 63) wsum[wid] = sc;
        __syncthreads();
        unsigned off = 0;
        for (int ww = 0; ww < wid; ww++) off += wsum[ww];
        sc += off;
        unsigned exc = sc - v;
        if ((int)sc >= krem && (int)exc < krem) { sel_s = tid; selexc_s = exc; }
        __syncthreads();
        prefix = (prefix << 8) | (unsigned)sel_s;
        krem -= (int)selexc_s;
        __syncthreads();
    }
    const unsigned thr = prefix;   // bit pattern of kth smallest |x|

    int cnt = 0;
    double l1 = 0.0;
    float* os = out_sparse + (size_t)row * 4096;
    float* om = out_mask + (size_t)row * 4096;
    for (int i = tid; i < 1024; i += 256) {
        float4 sv, mv;
        #pragma unroll
        for (int j = 0; j < 4; j++) {
            unsigned b = bits[i * 4 + j];
            unsigned a = b & 0x7fffffffu;
            bool m = a > thr;
            (&sv.x)[j] = m ? __uint_as_float(b) : 0.0f;
            (&mv.x)[j] = m ? 1.0f : 0.0f;
            if (m) { cnt++; l1 += (double)__uint_as_float(a); }
        }
        ((float4*)os)[i] = sv;
        ((float4*)om)[i] = mv;
    }
    #pragma unroll
    for (int o = 32; o > 0; o >>= 1) {
        cnt += __shfl_down(cnt, o, 64);
        l1  += __shfl_down(l1,  o, 64);
    }
    if (lane == 0) { cnt_w[wid] = cnt; l1_w[wid] = l1; }
    __syncthreads();
    if (tid == 0) {
        int c    = cnt_w[0] + cnt_w[1] + cnt_w[2] + cnt_w[3];
        double l = l1_w[0] + l1_w[1] + l1_w[2] + l1_w[3];
        out_actual[row] = (float)c / 4096.0f;
        l1rows[row] = l;
    }
}

// ---------------- k3: deterministic l1 mean (f64)
__global__ __launch_bounds__(256) void k3_l1(const double* __restrict__ l1rows,
                                             float* __restrict__ out_l1)
{
    __shared__ double sm[256];
    int tid = threadIdx.x;
    double s = 0.0;
    for (int i = tid; i < 4096; i += 256) s += l1rows[i];
    sm[tid] = s;
    __syncthreads();
    for (int st = 128; st > 0; st >>= 1) {
        if (tid < st) sm[tid] += sm[tid + st];
        __syncthreads();
    }
    if (tid == 0) out_l1[0] = (float)(sm[0] / 4096.0);
}

extern "C" void kernel_launch(void* const* d_in, const int* in_sizes, int n_in,
                              void* d_out, int out_size, void* d_ws, size_t ws_size,
                              hipStream_t stream)
{
    const float* x  = (const float*)d_in[0];
    const float* W1 = (const float*)d_in[1];
    const float* b1 = (const float*)d_in[2];
    const float* W2 = (const float*)d_in[3];
    const float* b2 = (const float*)d_in[4];

    float* out        = (float*)d_out;
    float* out_sparse = out;                       // [4096,4096]
    float* out_mask   = out + 16777216;            // [4096,4096]
    float* out_spars  = out + 33554432;            // [4096,1]
    float* out_actual = out + 33558528;            // [4096]
    float* out_l1     = out + 33562624;            // [1]

    // big scratch inside d_out's sparse region (consumed before k2 writes it)
    unsigned short* xa  = (unsigned short*)(out);               // 32MB
    unsigned short* waT = (unsigned short*)(out + 8388608);     // 8MB
    float*          plogit = out + 10485760;                    // 512KB, [4096][32]

    // small hot arrays in d_ws (read by k2/k3 -> must not alias outputs)
    char* ws = (char*)d_ws;
    int*    k_arr  = (int*)(ws);               // 16KB
    float*  sp_arr = (float*)(ws + 16384);     // 16KB
    double* l1rows = (double*)(ws + 32768);    // 32KB

    k0a_cvtx<<<16384, 256, 0, stream>>>(x, xa);
    k0b_cvtw<<<dim3(16, 64), 256, 0, stream>>>(W1, waT);
    k1z_zero<<<512, 256, 0, stream>>>(plogit);
    k1est<<<512, 512, 0, stream>>>(xa, waT, b1, W2, plogit);
    k1b_k<<<16, 256, 0, stream>>>(plogit, b2, k_arr, sp_arr);
    k2_row<<<4096, 256, 0, stream>>>(x, k_arr, sp_arr, out_sparse, out_mask,
                                     out_spars, out_actual, l1rows);
    k3_l1<<<1, 256, 0, stream>>>(l1rows, out_l1);
}